// Round 11
// baseline (453.912 us; speedup 1.0000x reference)
//
#include <hip/hip_runtime.h>
#include <hip/hip_bf16.h>
#include <math.h>

// ---------------------------------------------------------------------------
// NodeMLPModel: edge MLP (GEMM+BN+SELU+GEMM) -> scatter-mean -> node MLP.
// Round-11: R10 + T1 stored as FP8 e4m3 (HW cvt) -- halves the dominant
// 410MB T1 round-trip (gemm1n write + segsel read). BN1 stats still
// computed from exact f32 accumulators; quantization noise enters only the
// selu-mean (averages down by ~sqrt(deg) and again over K=128 downstream).
// segsel re-laned: lane=(q=lane&7 -> 16 cols, rp=lane>>3 -> 8 rows/iter),
// b128 loads. Packed column order p=(byte index) true col pi(p)=(p&7)*16+(p>>3)
// retained for T1q/Aggm/T2p.
// Fragment layout (m89/m91-verified):
//   A: lane holds A[lane&15][8*(lane>>4)+j]
//   B: lane holds B[8*(lane>>4)+j][lane&15]
//   D: lane holds D[4*(lane>>4)+r][lane&15]
// ---------------------------------------------------------------------------

typedef __attribute__((ext_vector_type(8))) short bfrag;
typedef __attribute__((ext_vector_type(4))) float f32x4;
typedef __attribute__((ext_vector_type(4))) float f4raw;
typedef __attribute__((ext_vector_type(2))) unsigned u32x2;
typedef __attribute__((ext_vector_type(4))) unsigned u32x4;

#define N_EDGES 800000
#define N_NODES 100000
#define BN_EPS 1e-5f

static __device__ __forceinline__ short f2bf(float f) {
    union { float f; unsigned u; } v; v.f = f;
    unsigned r = (v.u + 0x7FFFu + ((v.u >> 16) & 1u)) >> 16;  // RNE
    return (short)r;
}
static __device__ __forceinline__ float bf2f(short h) {
    union { unsigned u; float f; } v;
    v.u = ((unsigned)(unsigned short)h) << 16;
    return v.f;
}

static __device__ __forceinline__ bfrag load8f_bf(const float* __restrict__ p) {
    float4 a = *(const float4*)p;
    float4 b = *(const float4*)(p + 4);
    bfrag r;
    r[0] = f2bf(a.x); r[1] = f2bf(a.y); r[2] = f2bf(a.z); r[3] = f2bf(a.w);
    r[4] = f2bf(b.x); r[5] = f2bf(b.y); r[6] = f2bf(b.z); r[7] = f2bf(b.w);
    return r;
}
// nontemporal load (single-use streams only: ea)
static __device__ __forceinline__ bfrag load8f_bf_nt(const float* __restrict__ p) {
    f4raw a = __builtin_nontemporal_load((const f4raw*)p);
    f4raw b = __builtin_nontemporal_load((const f4raw*)(p + 4));
    bfrag r;
    r[0] = f2bf(a[0]); r[1] = f2bf(a[1]); r[2] = f2bf(a[2]); r[3] = f2bf(a[3]);
    r[4] = f2bf(b[0]); r[5] = f2bf(b[1]); r[6] = f2bf(b[2]); r[7] = f2bf(b[3]);
    return r;
}

static __device__ __forceinline__ float selu_f(float v) {
    return v > 0.f ? 1.0507009873554805f * v
                   : 1.7580993408473766f * (__expf(v) - 1.0f);
}

// ---------------------------------------------------------------------------
// prep: all weight packing + cb + histogram in ONE kernel.
static __device__ __forceinline__ void pack_slot(short* __restrict__ Wp, int k, int n, float val) {
    int kb = k >> 5, g = (k >> 3) & 3, j = k & 7;
    Wp[(((size_t)kb * 128 + n) * 4 + g) * 8 + j] = f2bf(val);
}

__global__ void prep(const float* __restrict__ W1a, const float* __restrict__ W1b,
                     const float* __restrict__ b1b, const float* __restrict__ W2a,
                     const float* __restrict__ W2b,
                     short* __restrict__ Wp1x, short* __restrict__ Wp1e,
                     short* __restrict__ Wp2a, short* __restrict__ Wp2b,
                     float* __restrict__ cb,
                     const int* __restrict__ colI, int* __restrict__ CNTi, int E)
{
    const int b = blockIdx.x, t = threadIdx.x;
    if (b < 64) {
        int idx = b * 256 + t; int k = idx >> 7, n = idx & 127;
        pack_slot(Wp1x, k, n, W1a[idx]);
    } else if (b < 96) {
        int idx = (b - 64) * 256 + t; int k = idx >> 7, n = idx & 127;
        pack_slot(Wp1e, k, n, W1a[128 * 128 + idx]);
    } else if (b < 160) {
        int idx = (b - 96) * 256 + t; int k = idx >> 7, n = idx & 127;
        pack_slot(Wp2a, k, n, W2a[idx]);
    } else if (b < 224) {
        // coalesced fold: half-block handles one packed-k
        int k = (b - 160) * 2 + (t >> 7);         // packed k, 0..127
        int n = t & 127;
        int kt = ((k & 7) << 4) + (k >> 3);       // perm: packed k -> true row
        float s = 0.f;
        for (int j = 0; j < 128; ++j)
            s += W1b[kt * 128 + j] * W2a[(size_t)(128 + j) * 128 + n];
        pack_slot(Wp2a + 16384, k, n, s);
    } else if (b < 288) {
        int idx = (b - 224) * 256 + t; int k = idx >> 7, n = idx & 127;
        pack_slot(Wp2a + 32768, k, n, W2a[(size_t)256 * 128 + idx]);
    } else if (b < 352) {
        int idx = (b - 288) * 256 + t; int k = idx >> 7, n = idx & 127;
        int kt = ((k & 7) << 4) + (k >> 3);
        pack_slot(Wp2b, k, n, W2b[(size_t)kt * 128 + n]);
    } else if (b == 352) {
        if (t < 128) {
            float s = 0.f;
            for (int j = 0; j < 128; ++j) s += b1b[j] * W2a[(size_t)(128 + j) * 128 + t];
            cb[t] = s;
        }
    } else {
        int e = (b - 353) * 256 + t;
        if (e < E) atomicAdd(&CNTi[colI[e]], 1);
    }
}

// ---------------------------------------------------------------------------
// scanF: single-kernel exclusive scan of CNTi -> OFF.
__global__ __launch_bounds__(1024) void scanF(const int* __restrict__ cnt,
                                              int* __restrict__ off, int N) {
    __shared__ int ls[1024];
    const int b = blockIdx.x, tid = threadIdx.x;
    int s = 0;
    const int lim = b * 1024;
    for (int i = tid; i < lim; i += 1024) s += cnt[i];
    ls[tid] = s;
    __syncthreads();
    for (int d = 512; d > 0; d >>= 1) {
        if (tid < d) ls[tid] += ls[tid + d];
        __syncthreads();
    }
    const int base = ls[0];
    __syncthreads();
    const int i = lim + tid;
    int v = (i < N) ? cnt[i] : 0;
    ls[tid] = v;
    __syncthreads();
    for (int d = 1; d < 1024; d <<= 1) {
        int t = (tid >= d) ? ls[tid - d] : 0;
        __syncthreads();
        ls[tid] += t;
        __syncthreads();
    }
    if (i < N) off[i] = base + ls[tid] - v;   // exclusive
}

// Consumes OFF (becomes end offsets: beg = OFF[v]-CNTi[v]).
// SPOS[e] = sorted position of edge e. Last block zeroes stats1/stats2.
__global__ void fill_k(const int* __restrict__ col, int* __restrict__ off,
                       int* __restrict__ spos, float* __restrict__ statsz, int E) {
    if (blockIdx.x == gridDim.x - 1) {
        statsz[threadIdx.x] = 0.f;
        statsz[256 + threadIdx.x] = 0.f;
        return;
    }
    int e = blockIdx.x * 256 + threadIdx.x;
    if (e < E) spos[e] = atomicAdd(&off[col[e]], 1);
}

// ---------------------------------------------------------------------------
// gemmX: Xap = packed bf16 of (x @ W1a[:128,:])
__global__ __launch_bounds__(256) void gemmX(
    const float* __restrict__ x, const short* __restrict__ Wp,
    short* __restrict__ Xap, int N)
{
    const int lane = threadIdx.x & 63, wave = threadIdx.x >> 6;
    const int m0 = blockIdx.x * 128 + wave * 32;
    if (m0 >= N) return;  // N % 32 == 0
    const int lr = lane & 15, lg = lane >> 4;
    const int v0 = m0 + lr, v1 = m0 + 16 + lr;

    f32x4 acc[2][8];
#pragma unroll
    for (int t = 0; t < 2; ++t)
#pragma unroll
        for (int n = 0; n < 8; ++n) acc[t][n] = (f32x4){0.f, 0.f, 0.f, 0.f};

#pragma unroll
    for (int kb = 0; kb < 4; ++kb) {
        bfrag a0 = load8f_bf(x + (size_t)v0 * 128 + kb * 32 + lg * 8);
        bfrag a1 = load8f_bf(x + (size_t)v1 * 128 + kb * 32 + lg * 8);
        const short* wb = Wp + (size_t)kb * 4096;
#pragma unroll
        for (int n0 = 0; n0 < 8; ++n0) {
            bfrag b = *(const bfrag*)(wb + ((n0 * 16 + lr) * 4 + lg) * 8);
            acc[0][n0] = __builtin_amdgcn_mfma_f32_16x16x32_bf16(a0, b, acc[0][n0], 0, 0, 0);
            acc[1][n0] = __builtin_amdgcn_mfma_f32_16x16x32_bf16(a1, b, acc[1][n0], 0, 0, 0);
        }
    }
#pragma unroll
    for (int t = 0; t < 2; ++t) {
        const int rbase = m0 + t * 16 + lg * 4;
#pragma unroll
        for (int r = 0; r < 4; ++r) {
            bfrag o;
#pragma unroll
            for (int n0 = 0; n0 < 8; ++n0) o[n0] = f2bf(acc[t][n0][r]);
            *(bfrag*)(Xap + (size_t)(rbase + r) * 128 + lr * 8) = o;
        }
    }
}

// ---------------------------------------------------------------------------
// gemm1n: T1q[SPOS[e]] = fp8e4m3(packed(ea[e] @ W1a[128:192] + Xa[row[e]]))
// Grid-stride tiles; Xap gathers hoisted; nontemporal ea loads;
// BN stats from exact f32 values; one atomic set per block.
__global__ __launch_bounds__(256) void gemm1n(
    const float* __restrict__ ea, const int* __restrict__ rowI,
    const int* __restrict__ SPOS, const short* __restrict__ Wp,
    const short* __restrict__ Xap, unsigned char* __restrict__ T1q,
    float* __restrict__ stats, int E)
{
    const int lane = threadIdx.x & 63, wave = threadIdx.x >> 6;
    const int lr = lane & 15, lg = lane >> 4;

    float ps[8], qs[8];
#pragma unroll
    for (int n0 = 0; n0 < 8; ++n0) { ps[n0] = 0.f; qs[n0] = 0.f; }

    const int NT = E >> 7;   // E % 128 == 0
    for (int tile = blockIdx.x; tile < NT; tile += gridDim.x) {
        const int m0 = tile * 128 + wave * 32;

        int spos[2][4];
        bfrag xa[2][4];
#pragma unroll
        for (int t = 0; t < 2; ++t) {
            const int rbase = m0 + t * 16 + lg * 4;
#pragma unroll
            for (int r = 0; r < 4; ++r) {
                const int e = rbase + r;
                spos[t][r] = SPOS[e];
                xa[t][r] = *(const bfrag*)(Xap + (size_t)rowI[e] * 128 + lr * 8);
            }
        }

        const float* er0 = ea + (size_t)(m0 + lr) * 64;
        const float* er1 = ea + (size_t)(m0 + 16 + lr) * 64;

        f32x4 acc[2][8];
#pragma unroll
        for (int t = 0; t < 2; ++t)
#pragma unroll
            for (int n = 0; n < 8; ++n) acc[t][n] = (f32x4){0.f, 0.f, 0.f, 0.f};

#pragma unroll
        for (int kb = 0; kb < 2; ++kb) {
            bfrag a0 = load8f_bf_nt(er0 + kb * 32 + lg * 8);
            bfrag a1 = load8f_bf_nt(er1 + kb * 32 + lg * 8);
            const short* wb = Wp + (size_t)kb * 4096;
#pragma unroll
            for (int n0 = 0; n0 < 8; ++n0) {
                bfrag b = *(const bfrag*)(wb + ((n0 * 16 + lr) * 4 + lg) * 8);
                acc[0][n0] = __builtin_amdgcn_mfma_f32_16x16x32_bf16(a0, b, acc[0][n0], 0, 0, 0);
                acc[1][n0] = __builtin_amdgcn_mfma_f32_16x16x32_bf16(a1, b, acc[1][n0], 0, 0, 0);
            }
        }

        // epilogue: add gathered Xa, stats (exact f32), fp8 pack, store 8B/lane
#pragma unroll
        for (int t = 0; t < 2; ++t) {
#pragma unroll
            for (int r = 0; r < 4; ++r) {
                float v[8];
#pragma unroll
                for (int n0 = 0; n0 < 8; ++n0) {
                    v[n0] = acc[t][n0][r] + bf2f(xa[t][r][n0]);
                    ps[n0] += v[n0]; qs[n0] += v[n0] * v[n0];
                }
                unsigned w0 = 0, w1 = 0;
                w0 = __builtin_amdgcn_cvt_pk_fp8_f32(v[0], v[1], w0, false);
                w0 = __builtin_amdgcn_cvt_pk_fp8_f32(v[2], v[3], w0, true);
                w1 = __builtin_amdgcn_cvt_pk_fp8_f32(v[4], v[5], w1, false);
                w1 = __builtin_amdgcn_cvt_pk_fp8_f32(v[6], v[7], w1, true);
                u32x2 o; o[0] = w0; o[1] = w1;
                *(u32x2*)(T1q + (size_t)spos[t][r] * 128 + lr * 8) = o;
            }
        }
    }

    __shared__ float ls[256];
    ls[threadIdx.x] = 0.f;
    __syncthreads();
#pragma unroll
    for (int n0 = 0; n0 < 8; ++n0) {
        const int c = n0 * 16 + lr;
        float p = ps[n0], q = qs[n0];
        p += __shfl_xor(p, 16); p += __shfl_xor(p, 32);
        q += __shfl_xor(q, 16); q += __shfl_xor(q, 32);
        if (lg == 0) { atomicAdd(&ls[c], p); atomicAdd(&ls[128 + c], q); }
    }
    __syncthreads();
    atomicAdd(&stats[threadIdx.x], ls[threadIdx.x]);
}

// ---------------------------------------------------------------------------
// segsel: Aggm[v] (packed bf16) = mean_{bucket} selu(BN1(fp8 T1q row))
// T1q bucket-contiguous; lane = (q=lane&7 -> 16 packed cols, rp=lane>>3 ->
// 8 rows in flight); b128 loads (16B/lane, 1KB/wave-instr); 3-step shfl.
__global__ __launch_bounds__(256) void segsel(
    const unsigned char* __restrict__ T1q, const float* __restrict__ stats,
    const float* __restrict__ g1, const float* __restrict__ be1,
    const int* __restrict__ OFF, const int* __restrict__ CNTi,
    short* __restrict__ Aggm, int N, float invR)
{
    __shared__ float ls_sc[128], ls_sh[128];
    if (threadIdx.x < 128) {
        int p = threadIdx.x;
        int c = ((p & 7) << 4) + (p >> 3);       // packed pos -> true col
        float mean = stats[c] * invR;
        float var = stats[128 + c] * invR - mean * mean;
        float sc = g1[c] * rsqrtf(var + BN_EPS);
        ls_sc[p] = sc;
        ls_sh[p] = be1[c] - mean * sc;
    }
    __syncthreads();

    const int lane = threadIdx.x & 63;
    const int q = lane & 7, rp = lane >> 3;     // q: 16-col group, rp: row 0..7
    const int wid = blockIdx.x * 4 + (threadIdx.x >> 6);
    const int nw = gridDim.x * 4;
    const int chunk = (N + nw - 1) / nw;
    const int v0 = wid * chunk;
    const int v1 = (v0 + chunk < N) ? v0 + chunk : N;

    float sc16[16], sh16[16];
#pragma unroll
    for (int i = 0; i < 16; ++i) { sc16[i] = ls_sc[q * 16 + i]; sh16[i] = ls_sh[q * 16 + i]; }

    for (int v = v0; v < v1; ++v) {
        const int cnt = CNTi[v];
        const int beg = OFF[v] - cnt;   // fill_k advanced OFF to end
        const unsigned char* base = T1q + (size_t)beg * 128 + q * 16;
        float a[16];
#pragma unroll
        for (int i = 0; i < 16; ++i) a[i] = 0.f;
        int j = 0;
        for (; j + 8 <= cnt; j += 8) {
            u32x4 w = *(const u32x4*)(base + (size_t)(j + rp) * 128);
#pragma unroll
            for (int wi = 0; wi < 4; ++wi) {
                a[wi * 4 + 0] += selu_f(sc16[wi * 4 + 0] * __builtin_amdgcn_cvt_f32_fp8(w[wi], 0) + sh16[wi * 4 + 0]);
                a[wi * 4 + 1] += selu_f(sc16[wi * 4 + 1] * __builtin_amdgcn_cvt_f32_fp8(w[wi], 1) + sh16[wi * 4 + 1]);
                a[wi * 4 + 2] += selu_f(sc16[wi * 4 + 2] * __builtin_amdgcn_cvt_f32_fp8(w[wi], 2) + sh16[wi * 4 + 2]);
                a[wi * 4 + 3] += selu_f(sc16[wi * 4 + 3] * __builtin_amdgcn_cvt_f32_fp8(w[wi], 3) + sh16[wi * 4 + 3]);
            }
        }
        if (j + rp < cnt) {
            u32x4 w = *(const u32x4*)(base + (size_t)(j + rp) * 128);
#pragma unroll
            for (int wi = 0; wi < 4; ++wi) {
                a[wi * 4 + 0] += selu_f(sc16[wi * 4 + 0] * __builtin_amdgcn_cvt_f32_fp8(w[wi], 0) + sh16[wi * 4 + 0]);
                a[wi * 4 + 1] += selu_f(sc16[wi * 4 + 1] * __builtin_amdgcn_cvt_f32_fp8(w[wi], 1) + sh16[wi * 4 + 1]);
                a[wi * 4 + 2] += selu_f(sc16[wi * 4 + 2] * __builtin_amdgcn_cvt_f32_fp8(w[wi], 2) + sh16[wi * 4 + 2]);
                a[wi * 4 + 3] += selu_f(sc16[wi * 4 + 3] * __builtin_amdgcn_cvt_f32_fp8(w[wi], 3) + sh16[wi * 4 + 3]);
            }
        }
#pragma unroll
        for (int i = 0; i < 16; ++i) {
            a[i] += __shfl_xor(a[i], 8);
            a[i] += __shfl_xor(a[i], 16);
            a[i] += __shfl_xor(a[i], 32);
        }
        if (rp == 0) {
            const float inv = 1.0f / fmaxf((float)cnt, 1.0f);
            bfrag o0, o1;
#pragma unroll
            for (int i = 0; i < 8; ++i) {
                o0[i] = f2bf(a[i] * inv);
                o1[i] = f2bf(a[8 + i] * inv);
            }
            *(bfrag*)(Aggm + (size_t)v * 128 + q * 16) = o0;
            *(bfrag*)(Aggm + (size_t)v * 128 + q * 16 + 8) = o1;
        }
    }
}

// ---------------------------------------------------------------------------
// gemm3: T2p = packed([x, Aggm(packed), u[batch]] @ W2a' + (deg>0)*cb) ; fused stats
__global__ __launch_bounds__(256) void gemm3_node(
    const float* __restrict__ x, const short* __restrict__ Aggm,
    const float* __restrict__ u, const int* __restrict__ batch,
    const int* __restrict__ CNTi, const float* __restrict__ cb,
    const short* __restrict__ Wp, short* __restrict__ T2p,
    float* __restrict__ stats, int N)
{
    const int lane = threadIdx.x & 63, wave = threadIdx.x >> 6;
    const int m0 = blockIdx.x * 128 + wave * 32;
    const bool active = (m0 < N);   // N % 32 == 0
    const int lr = lane & 15, lg = lane >> 4;
    __shared__ float ls[256];
    ls[threadIdx.x] = 0.f;
    __syncthreads();

    if (active) {
        const int v0 = m0 + lr, v1 = m0 + 16 + lr;
        const float* u0 = u + (size_t)batch[v0] * 128;
        const float* u1 = u + (size_t)batch[v1] * 128;

        f32x4 acc[2][8];
#pragma unroll
        for (int t = 0; t < 2; ++t)
#pragma unroll
            for (int n = 0; n < 8; ++n) acc[t][n] = (f32x4){0.f, 0.f, 0.f, 0.f};

#pragma unroll
        for (int kb = 0; kb < 12; ++kb) {
            bfrag a0, a1;
            if (kb >= 4 && kb < 8) {
                a0 = *(const bfrag*)(Aggm + (size_t)v0 * 128 + (kb - 4) * 32 + lg * 8);
                a1 = *(const bfrag*)(Aggm + (size_t)v1 * 128 + (kb - 4) * 32 + lg * 8);
            } else {
                const float *p0, *p1;
                if (kb < 4) {
                    p0 = x + (size_t)v0 * 128 + kb * 32 + lg * 8;
                    p1 = x + (size_t)v1 * 128 + kb * 32 + lg * 8;
                } else {
                    p0 = u0 + (kb - 8) * 32 + lg * 8;
                    p1 = u1 + (kb - 8) * 32 + lg * 8;
                }
                a0 = load8f_bf(p0);
                a1 = load8f_bf(p1);
            }
            const short* wb = Wp + (size_t)kb * 4096;
#pragma unroll
            for (int n0 = 0; n0 < 8; ++n0) {
                bfrag b = *(const bfrag*)(wb + ((n0 * 16 + lr) * 4 + lg) * 8);
                acc[0][n0] = __builtin_amdgcn_mfma_f32_16x16x32_bf16(a0, b, acc[0][n0], 0, 0, 0);
                acc[1][n0] = __builtin_amdgcn_mfma_f32_16x16x32_bf16(a1, b, acc[1][n0], 0, 0, 0);
            }
        }
        float cbl[8];
#pragma unroll
        for (int n0 = 0; n0 < 8; ++n0) cbl[n0] = cb[n0 * 16 + lr];
        float ps[8], qs[8];
#pragma unroll
        for (int n0 = 0; n0 < 8; ++n0) { ps[n0] = 0.f; qs[n0] = 0.f; }
#pragma unroll
        for (int t = 0; t < 2; ++t) {
            const int rbase = m0 + t * 16 + lg * 4;
            float fl[4];
#pragma unroll
            for (int r = 0; r < 4; ++r) fl[r] = (CNTi[rbase + r] > 0) ? 1.f : 0.f;
#pragma unroll
            for (int r = 0; r < 4; ++r) {
                bfrag o;
#pragma unroll
                for (int n0 = 0; n0 < 8; ++n0) {
                    float v = acc[t][n0][r] + fl[r] * cbl[n0];
                    ps[n0] += v; qs[n0] += v * v;
                    o[n0] = f2bf(v);
                }
                *(bfrag*)(T2p + (size_t)(rbase + r) * 128 + lr * 8) = o;
            }
        }
#pragma unroll
        for (int n0 = 0; n0 < 8; ++n0) {
            const int c = n0 * 16 + lr;
            float p = ps[n0], q = qs[n0];
            p += __shfl_xor(p, 16); p += __shfl_xor(p, 32);
            q += __shfl_xor(q, 16); q += __shfl_xor(q, 32);
            if (lg == 0) { atomicAdd(&ls[c], p); atomicAdd(&ls[128 + c], q); }
        }
    }
    __syncthreads();
    atomicAdd(&stats[threadIdx.x], ls[threadIdx.x]);
}

// Node GEMM2: out = selu(BN2(T2p)) @ W2b' + b2b   (f32 true-order output)
__global__ __launch_bounds__(256) void gemm4_node(
    const short* __restrict__ T2p, const float* __restrict__ stats,
    const float* __restrict__ g2, const float* __restrict__ be2,
    const short* __restrict__ Wp, const float* __restrict__ b2b,
    float* __restrict__ out, int N, float invR)
{
    __shared__ float ls_sc[128], ls_sh[128];
    if (threadIdx.x < 128) {
        int c = threadIdx.x;                     // true col
        float mean = stats[c] * invR;
        float var = stats[128 + c] * invR - mean * mean;
        float sc = g2[c] * rsqrtf(var + BN_EPS);
        ls_sc[c] = sc;
        ls_sh[c] = be2[c] - mean * sc;
    }
    __syncthreads();

    const int lane = threadIdx.x & 63, wave = threadIdx.x >> 6;
    const int m0 = blockIdx.x * 128 + wave * 32;
    if (m0 >= N) return;   // N % 32 == 0
    const int lr = lane & 15, lg = lane >> 4;
    const int e0 = m0 + lr, e1 = m0 + 16 + lr;

    f32x4 acc[2][8];
#pragma unroll
    for (int n0 = 0; n0 < 8; ++n0) {
        float bias = b2b[n0 * 16 + lr];
        acc[0][n0] = (f32x4){bias, bias, bias, bias};
        acc[1][n0] = (f32x4){bias, bias, bias, bias};
    }
#pragma unroll
    for (int kb = 0; kb < 4; ++kb) {
        // packed pos p = kb*32+lg*8+j  ->  true col j*16 + kb*4 + lg
        float scl[8], shf[8];
#pragma unroll
        for (int j = 0; j < 8; ++j) {
            int c = j * 16 + kb * 4 + lg;
            scl[j] = ls_sc[c];
            shf[j] = ls_sh[c];
        }
        bfrag r0 = *(const bfrag*)(T2p + (size_t)e0 * 128 + kb * 32 + lg * 8);
        bfrag r1 = *(const bfrag*)(T2p + (size_t)e1 * 128 + kb * 32 + lg * 8);
        bfrag a0, a1;
#pragma unroll
        for (int j = 0; j < 8; ++j) {
            a0[j] = f2bf(selu_f(bf2f(r0[j]) * scl[j] + shf[j]));
            a1[j] = f2bf(selu_f(bf2f(r1[j]) * scl[j] + shf[j]));
        }
        const short* wb = Wp + (size_t)kb * 4096;
#pragma unroll
        for (int n0 = 0; n0 < 8; ++n0) {
            bfrag b = *(const bfrag*)(wb + ((n0 * 16 + lr) * 4 + lg) * 8);
            acc[0][n0] = __builtin_amdgcn_mfma_f32_16x16x32_bf16(a0, b, acc[0][n0], 0, 0, 0);
            acc[1][n0] = __builtin_amdgcn_mfma_f32_16x16x32_bf16(a1, b, acc[1][n0], 0, 0, 0);
        }
    }
#pragma unroll
    for (int t = 0; t < 2; ++t) {
        const int rbase = m0 + t * 16 + lg * 4;
#pragma unroll
        for (int n0 = 0; n0 < 8; ++n0) {
            const int c = n0 * 16 + lr;
#pragma unroll
            for (int r = 0; r < 4; ++r)
                __builtin_nontemporal_store(acc[t][n0][r],
                    out + (size_t)(rbase + r) * 128 + c);
        }
    }
}

// ---------------------------------------------------------------------------
// Workspace layout (bytes):
//   0        Wp1x 32768  | 32768 Wp1e 16384 | 49152 Wp2a 98304 | 147456 Wp2b 32768
//   245760   cb 512
//   246272   stats1 1024 | 247296 stats2 1024   (zeroed by fill_k's last block)
//   250368   CNTi 400000 | 650368 OFF 400000
//   1052416  SPOS 3200000
//   4252416  Aggm bf16 100000x128 (25600000)
//   29852416 Xap bf16 100000x128 (25600000)  [phase2: T2p overlays]
//   55452416 T1q fp8 800000x128 (102400000)  [CSR-sorted row order]
//   total: 157852416
// ---------------------------------------------------------------------------
extern "C" void kernel_launch(void* const* d_in, const int* in_sizes, int n_in,
                              void* d_out, int out_size, void* d_ws, size_t ws_size,
                              hipStream_t stream)
{
    const float* x   = (const float*)d_in[0];
    const float* ea  = (const float*)d_in[1];
    const float* u   = (const float*)d_in[2];
    const float* W1a = (const float*)d_in[3];
    // d_in[4] = b1a: cancels in BN1
    const float* g1  = (const float*)d_in[5];
    const float* be1 = (const float*)d_in[6];
    const float* W1b = (const float*)d_in[7];
    const float* b1b = (const float*)d_in[8];
    const float* W2a = (const float*)d_in[9];
    // d_in[10] = b2a: cancels in BN2
    const float* g2  = (const float*)d_in[11];
    const float* be2 = (const float*)d_in[12];
    const float* W2b = (const float*)d_in[13];
    const float* b2b = (const float*)d_in[14];
    const int* ei    = (const int*)d_in[15];
    const int* rowI  = ei;
    const int* colI  = ei + N_EDGES;
    const int* batch = (const int*)d_in[16];
    float* out = (float*)d_out;

    if (ws_size < 157852416ull) return;

    char* ws = (char*)d_ws;
    short* Wp1x   = (short*)(ws + 0);
    short* Wp1e   = (short*)(ws + 32768);
    short* Wp2a   = (short*)(ws + 49152);
    short* Wp2b   = (short*)(ws + 147456);
    float* cb     = (float*)(ws + 245760);
    float* stats1 = (float*)(ws + 246272);
    float* stats2 = (float*)(ws + 247296);
    int*   CNTi   = (int*)(ws + 250368);
    int*   OFF    = (int*)(ws + 650368);
    int*   SPOS   = (int*)(ws + 1052416);
    short* Aggm   = (short*)(ws + 4252416);
    short* Xap    = (short*)(ws + 29852416ull);
    short* T2p    = (short*)(ws + 29852416ull);   // overlays Xap (dead after gemm1n)
    unsigned char* T1q = (unsigned char*)(ws + 55452416ull);

    hipMemsetAsync(CNTi, 0, 400000, stream);

    // all weight prep + histogram: one kernel
    prep<<<353 + (N_EDGES + 255) / 256, 256, 0, stream>>>(
        W1a, W1b, b1b, W2a, W2b, Wp1x, Wp1e, Wp2a, Wp2b, cb, colI, CNTi, N_EDGES);

    // single-kernel exclusive scan + inverse-perm fill (+stats zeroing)
    scanF<<<98, 1024, 0, stream>>>(CNTi, OFF, N_NODES);
    fill_k<<<(N_EDGES + 255) / 256 + 1, 256, 0, stream>>>(colI, OFF, SPOS, stats1, N_EDGES);

    // node-side half of edge layer 1
    gemmX<<<(N_NODES + 127) / 128, 256, 0, stream>>>(x, Wp1x, Xap, N_NODES);

    // edge layer 1 (natural read order, sorted fp8 write order) + stats
    gemm1n<<<2048, 256, 0, stream>>>(ea, rowI, SPOS, Wp1e, Xap, T1q, stats1, N_EDGES);

    // segmented selu-mean over bucket-contiguous fp8 T1q; BN1 inline
    segsel<<<2048, 256, 0, stream>>>(T1q, stats1, g1, be1, OFF, CNTi, Aggm,
                                     N_NODES, 1.0f / (float)N_EDGES);

    // node MLP
    gemm3_node<<<(N_NODES + 127) / 128, 256, 0, stream>>>(x, Aggm, u, batch, CNTi, cb,
                                                          Wp2a, T2p, stats2, N_NODES);
    gemm4_node<<<(N_NODES + 127) / 128, 256, 0, stream>>>(T2p, stats2, g2, be2, Wp2b, b2b,
                                                          out, N_NODES, 1.0f / (float)N_NODES);
}

// Round 12
// 371.015 us; speedup vs baseline: 1.2234x; 1.2234x over previous
//
#include <hip/hip_runtime.h>
#include <hip/hip_bf16.h>
#include <math.h>

// ---------------------------------------------------------------------------
// NodeMLPModel: edge MLP (GEMM+BN+SELU+GEMM) -> scatter-mean -> node MLP.
// Round-12 = Round-8 exact revert (best measured: 370.3 us).
// fp8 T1 (R11) disqualified: VGPR 124->148 cut occupancy 20->11%, scatter
// segments 256B->128B -> gemm1n 121->178us; absmax 0.031->0.070.
// Structure: single prep kernel; CSR build; gemmX (node-side half of edge
// layer 1); gemm1n grid-stride with register BN stats + nt streams, sorted
// scatter-write of packed T1p; segsel streaming selu-mean; lean gemm3/gemm4.
// Packed column order p=lr*8+n0 (true col pi(p)=(p&7)*16+(p>>3)) for
// T1p/Aggm/T2p.
// Fragment layout (m89/m91-verified):
//   A: lane holds A[lane&15][8*(lane>>4)+j]
//   B: lane holds B[8*(lane>>4)+j][lane&15]
//   D: lane holds D[4*(lane>>4)+r][lane&15]
// ---------------------------------------------------------------------------

typedef __attribute__((ext_vector_type(8))) short bfrag;
typedef __attribute__((ext_vector_type(4))) float f32x4;
typedef __attribute__((ext_vector_type(4))) float f4raw;
typedef __attribute__((ext_vector_type(2))) unsigned u32x2;

#define N_EDGES 800000
#define N_NODES 100000
#define BN_EPS 1e-5f

static __device__ __forceinline__ short f2bf(float f) {
    union { float f; unsigned u; } v; v.f = f;
    unsigned r = (v.u + 0x7FFFu + ((v.u >> 16) & 1u)) >> 16;  // RNE
    return (short)r;
}
static __device__ __forceinline__ float bf2f(short h) {
    union { unsigned u; float f; } v;
    v.u = ((unsigned)(unsigned short)h) << 16;
    return v.f;
}
static __device__ __forceinline__ unsigned pack2(float lo, float hi) {
    return ((unsigned)(unsigned short)f2bf(lo)) | (((unsigned)(unsigned short)f2bf(hi)) << 16);
}

static __device__ __forceinline__ bfrag load8f_bf(const float* __restrict__ p) {
    float4 a = *(const float4*)p;
    float4 b = *(const float4*)(p + 4);
    bfrag r;
    r[0] = f2bf(a.x); r[1] = f2bf(a.y); r[2] = f2bf(a.z); r[3] = f2bf(a.w);
    r[4] = f2bf(b.x); r[5] = f2bf(b.y); r[6] = f2bf(b.z); r[7] = f2bf(b.w);
    return r;
}
// nontemporal variants (streaming data: bypass cache retention)
static __device__ __forceinline__ bfrag load8f_bf_nt(const float* __restrict__ p) {
    f4raw a = __builtin_nontemporal_load((const f4raw*)p);
    f4raw b = __builtin_nontemporal_load((const f4raw*)(p + 4));
    bfrag r;
    r[0] = f2bf(a[0]); r[1] = f2bf(a[1]); r[2] = f2bf(a[2]); r[3] = f2bf(a[3]);
    r[4] = f2bf(b[0]); r[5] = f2bf(b[1]); r[6] = f2bf(b[2]); r[7] = f2bf(b[3]);
    return r;
}
static __device__ __forceinline__ u32x2 ldnt_u2(const short* p) {
    return __builtin_nontemporal_load((const u32x2*)p);
}
static __device__ __forceinline__ void stnt_frag(short* p, bfrag v) {
    __builtin_nontemporal_store(v, (bfrag*)p);
}

static __device__ __forceinline__ float selu_f(float v) {
    return v > 0.f ? 1.0507009873554805f * v
                   : 1.7580993408473766f * (__expf(v) - 1.0f);
}

// ---------------------------------------------------------------------------
// prep: all weight packing + cb + histogram in ONE kernel.
static __device__ __forceinline__ void pack_slot(short* __restrict__ Wp, int k, int n, float val) {
    int kb = k >> 5, g = (k >> 3) & 3, j = k & 7;
    Wp[(((size_t)kb * 128 + n) * 4 + g) * 8 + j] = f2bf(val);
}

__global__ void prep(const float* __restrict__ W1a, const float* __restrict__ W1b,
                     const float* __restrict__ b1b, const float* __restrict__ W2a,
                     const float* __restrict__ W2b,
                     short* __restrict__ Wp1x, short* __restrict__ Wp1e,
                     short* __restrict__ Wp2a, short* __restrict__ Wp2b,
                     float* __restrict__ cb,
                     const int* __restrict__ colI, int* __restrict__ CNTi, int E)
{
    const int b = blockIdx.x, t = threadIdx.x;
    if (b < 64) {
        int idx = b * 256 + t; int k = idx >> 7, n = idx & 127;
        pack_slot(Wp1x, k, n, W1a[idx]);
    } else if (b < 96) {
        int idx = (b - 64) * 256 + t; int k = idx >> 7, n = idx & 127;
        pack_slot(Wp1e, k, n, W1a[128 * 128 + idx]);
    } else if (b < 160) {
        int idx = (b - 96) * 256 + t; int k = idx >> 7, n = idx & 127;
        pack_slot(Wp2a, k, n, W2a[idx]);
    } else if (b < 224) {
        int idx = (b - 160) * 256 + t; int k = idx >> 7, n = idx & 127;
        int kt = ((k & 7) << 4) + (k >> 3);       // perm: packed k -> true row
        float s = 0.f;
        for (int j = 0; j < 128; ++j)
            s += W1b[kt * 128 + j] * W2a[(size_t)(128 + j) * 128 + n];
        pack_slot(Wp2a + 16384, k, n, s);
    } else if (b < 288) {
        int idx = (b - 224) * 256 + t; int k = idx >> 7, n = idx & 127;
        pack_slot(Wp2a + 32768, k, n, W2a[(size_t)256 * 128 + idx]);
    } else if (b < 352) {
        int idx = (b - 288) * 256 + t; int k = idx >> 7, n = idx & 127;
        int kt = ((k & 7) << 4) + (k >> 3);
        pack_slot(Wp2b, k, n, W2b[(size_t)kt * 128 + n]);
    } else if (b == 352) {
        if (t < 128) {
            float s = 0.f;
            for (int j = 0; j < 128; ++j) s += b1b[j] * W2a[(size_t)(128 + j) * 128 + t];
            cb[t] = s;
        }
    } else {
        int e = (b - 353) * 256 + t;
        if (e < E) atomicAdd(&CNTi[colI[e]], 1);
    }
}

// ----------------------------- CSR scan + fill ------------------------------
__global__ void scan1(const int* __restrict__ cnt, int* __restrict__ off,
                      int* __restrict__ bsum, int N) {
    __shared__ int ls[1024];
    int i = blockIdx.x * 1024 + threadIdx.x;
    int v = (i < N) ? cnt[i] : 0;
    ls[threadIdx.x] = v;
    __syncthreads();
    for (int d = 1; d < 1024; d <<= 1) {
        int t = (threadIdx.x >= d) ? ls[threadIdx.x - d] : 0;
        __syncthreads();
        ls[threadIdx.x] += t;
        __syncthreads();
    }
    if (i < N) off[i] = ls[threadIdx.x] - v;
    if (threadIdx.x == 1023) bsum[blockIdx.x] = ls[1023];
}

__global__ void scan2(const int* __restrict__ bsum, int* __restrict__ boff, int NB) {
    __shared__ int ls[128];
    int v = (threadIdx.x < NB) ? bsum[threadIdx.x] : 0;
    ls[threadIdx.x] = v;
    __syncthreads();
    for (int d = 1; d < 128; d <<= 1) {
        int t = (threadIdx.x >= d) ? ls[threadIdx.x - d] : 0;
        __syncthreads();
        ls[threadIdx.x] += t;
        __syncthreads();
    }
    if (threadIdx.x < NB) boff[threadIdx.x] = ls[threadIdx.x] - v;
}

__global__ void scan3(int* __restrict__ off, const int* __restrict__ boff, int N) {
    int i = blockIdx.x * 1024 + threadIdx.x;
    if (i < N) off[i] += boff[blockIdx.x];
}

// Consumes OFF (becomes end offsets: beg = OFF[v]-CNTi[v]).
// SPOS[e] = sorted position of edge e (inverse permutation).
__global__ void fill_k(const int* __restrict__ col, int* __restrict__ off,
                       int* __restrict__ spos, int E) {
    int e = blockIdx.x * 256 + threadIdx.x;
    if (e < E) spos[e] = atomicAdd(&off[col[e]], 1);
}

// ---------------------------------------------------------------------------
// gemmX: Xap = packed bf16 of (x @ W1a[:128,:])
// Layout: Xap[v*128 + lr*8 + n0] = Xa[v][n0*16+lr]
__global__ __launch_bounds__(256) void gemmX(
    const float* __restrict__ x, const short* __restrict__ Wp,
    short* __restrict__ Xap, int N)
{
    const int lane = threadIdx.x & 63, wave = threadIdx.x >> 6;
    const int m0 = blockIdx.x * 128 + wave * 32;
    if (m0 >= N) return;  // N % 32 == 0
    const int lr = lane & 15, lg = lane >> 4;
    const int v0 = m0 + lr, v1 = m0 + 16 + lr;

    f32x4 acc[2][8];
#pragma unroll
    for (int t = 0; t < 2; ++t)
#pragma unroll
        for (int n = 0; n < 8; ++n) acc[t][n] = (f32x4){0.f, 0.f, 0.f, 0.f};

#pragma unroll
    for (int kb = 0; kb < 4; ++kb) {
        bfrag a0 = load8f_bf(x + (size_t)v0 * 128 + kb * 32 + lg * 8);
        bfrag a1 = load8f_bf(x + (size_t)v1 * 128 + kb * 32 + lg * 8);
        const short* wb = Wp + (size_t)kb * 4096;
#pragma unroll
        for (int n0 = 0; n0 < 8; ++n0) {
            bfrag b = *(const bfrag*)(wb + ((n0 * 16 + lr) * 4 + lg) * 8);
            acc[0][n0] = __builtin_amdgcn_mfma_f32_16x16x32_bf16(a0, b, acc[0][n0], 0, 0, 0);
            acc[1][n0] = __builtin_amdgcn_mfma_f32_16x16x32_bf16(a1, b, acc[1][n0], 0, 0, 0);
        }
    }
#pragma unroll
    for (int t = 0; t < 2; ++t) {
        const int rbase = m0 + t * 16 + lg * 4;
#pragma unroll
        for (int r = 0; r < 4; ++r) {
            bfrag o;
#pragma unroll
            for (int n0 = 0; n0 < 8; ++n0) o[n0] = f2bf(acc[t][n0][r]);
            *(bfrag*)(Xap + (size_t)(rbase + r) * 128 + lr * 8) = o;
        }
    }
}

// ---------------------------------------------------------------------------
// gemm1n: T1p[SPOS[e]] = packed(ea[e] @ W1a[128:192] + Xa[row[e]])
// Grid-stride tiles; Xap gathers hoisted; nontemporal ea loads + T1p stores;
// BN stats accumulated in registers across tiles, one atomic set per block.
__global__ __launch_bounds__(256) void gemm1n(
    const float* __restrict__ ea, const int* __restrict__ rowI,
    const int* __restrict__ SPOS, const short* __restrict__ Wp,
    const short* __restrict__ Xap, short* __restrict__ T1p,
    float* __restrict__ stats, int E)
{
    const int lane = threadIdx.x & 63, wave = threadIdx.x >> 6;
    const int lr = lane & 15, lg = lane >> 4;

    float ps[8], qs[8];
#pragma unroll
    for (int n0 = 0; n0 < 8; ++n0) { ps[n0] = 0.f; qs[n0] = 0.f; }

    const int NT = E >> 7;   // E % 128 == 0
    for (int tile = blockIdx.x; tile < NT; tile += gridDim.x) {
        const int m0 = tile * 128 + wave * 32;

        // hoisted: indices + Xa gathers (latency hidden under ea loads+MFMA)
        int spos[2][4];
        bfrag xa[2][4];
#pragma unroll
        for (int t = 0; t < 2; ++t) {
            const int rbase = m0 + t * 16 + lg * 4;
#pragma unroll
            for (int r = 0; r < 4; ++r) {
                const int e = rbase + r;
                spos[t][r] = SPOS[e];
                xa[t][r] = *(const bfrag*)(Xap + (size_t)rowI[e] * 128 + lr * 8);
            }
        }

        const float* er0 = ea + (size_t)(m0 + lr) * 64;
        const float* er1 = ea + (size_t)(m0 + 16 + lr) * 64;

        f32x4 acc[2][8];
#pragma unroll
        for (int t = 0; t < 2; ++t)
#pragma unroll
            for (int n = 0; n < 8; ++n) acc[t][n] = (f32x4){0.f, 0.f, 0.f, 0.f};

#pragma unroll
        for (int kb = 0; kb < 2; ++kb) {
            bfrag a0 = load8f_bf_nt(er0 + kb * 32 + lg * 8);
            bfrag a1 = load8f_bf_nt(er1 + kb * 32 + lg * 8);
            const short* wb = Wp + (size_t)kb * 4096;
#pragma unroll
            for (int n0 = 0; n0 < 8; ++n0) {
                bfrag b = *(const bfrag*)(wb + ((n0 * 16 + lr) * 4 + lg) * 8);
                acc[0][n0] = __builtin_amdgcn_mfma_f32_16x16x32_bf16(a0, b, acc[0][n0], 0, 0, 0);
                acc[1][n0] = __builtin_amdgcn_mfma_f32_16x16x32_bf16(a1, b, acc[1][n0], 0, 0, 0);
            }
        }

        // epilogue: add gathered Xa, accumulate stats, scatter-store (256B segs)
#pragma unroll
        for (int t = 0; t < 2; ++t) {
#pragma unroll
            for (int r = 0; r < 4; ++r) {
                bfrag o;
#pragma unroll
                for (int n0 = 0; n0 < 8; ++n0) {
                    float v = acc[t][n0][r] + bf2f(xa[t][r][n0]);
                    ps[n0] += v; qs[n0] += v * v;
                    o[n0] = f2bf(v);
                }
                stnt_frag(T1p + (size_t)spos[t][r] * 128 + lr * 8, o);
            }
        }
    }

    // one stats reduction per block
    __shared__ float ls[256];
    ls[threadIdx.x] = 0.f;
    __syncthreads();
#pragma unroll
    for (int n0 = 0; n0 < 8; ++n0) {
        const int c = n0 * 16 + lr;
        float p = ps[n0], q = qs[n0];
        p += __shfl_xor(p, 16); p += __shfl_xor(p, 32);
        q += __shfl_xor(q, 16); q += __shfl_xor(q, 32);
        if (lg == 0) { atomicAdd(&ls[c], p); atomicAdd(&ls[128 + c], q); }
    }
    __syncthreads();
    atomicAdd(&stats[threadIdx.x], ls[threadIdx.x]);
}

// ---------------------------------------------------------------------------
// segsel: Aggm[v] (packed) = (1/max(deg,1)) * sum_{rows in bucket(v)} selu(BN1(T1p))
// T1p is bucket-contiguous -> pure sequential nt reads. Half-wave per row,
// contiguous node chunks per wave. BN params from stats in block prologue.
__global__ __launch_bounds__(256) void segsel(
    const short* __restrict__ T1p, const float* __restrict__ stats,
    const float* __restrict__ g1, const float* __restrict__ be1,
    const int* __restrict__ OFF, const int* __restrict__ CNTi,
    short* __restrict__ Aggm, int N, float invR)
{
    __shared__ float ls_sc[128], ls_sh[128];
    if (threadIdx.x < 128) {
        int p = threadIdx.x;
        int c = ((p & 7) << 4) + (p >> 3);       // true col
        float mean = stats[c] * invR;
        float var = stats[128 + c] * invR - mean * mean;
        float sc = g1[c] * rsqrtf(var + BN_EPS);
        ls_sc[p] = sc;
        ls_sh[p] = be1[c] - mean * sc;
    }
    __syncthreads();

    const int lane = threadIdx.x & 63;
    const int h = lane >> 5, t = lane & 31;
    const int wid = blockIdx.x * 4 + (threadIdx.x >> 6);
    const int nw = gridDim.x * 4;
    const int chunk = (N + nw - 1) / nw;
    const int v0 = wid * chunk;
    const int v1 = (v0 + chunk < N) ? v0 + chunk : N;

    const float sc0 = ls_sc[t * 4 + 0], sc1 = ls_sc[t * 4 + 1];
    const float sc2 = ls_sc[t * 4 + 2], sc3 = ls_sc[t * 4 + 3];
    const float sh0 = ls_sh[t * 4 + 0], sh1 = ls_sh[t * 4 + 1];
    const float sh2 = ls_sh[t * 4 + 2], sh3 = ls_sh[t * 4 + 3];

    for (int v = v0; v < v1; ++v) {
        const int cnt = CNTi[v];
        const int beg = OFF[v] - cnt;   // fill_k advanced OFF to end
        const short* base = T1p + (size_t)beg * 128 + t * 4;
        float a0 = 0.f, a1 = 0.f, a2 = 0.f, a3 = 0.f;
        int j = 0;
        for (; j + 4 <= cnt; j += 4) {
            u32x2 wA = ldnt_u2(base + (size_t)(j + h) * 128);
            u32x2 wB = ldnt_u2(base + (size_t)(j + 2 + h) * 128);
            a0 += selu_f(sc0 * bf2f((short)(wA[0] & 0xffff)) + sh0);
            a1 += selu_f(sc1 * bf2f((short)(wA[0] >> 16)) + sh1);
            a2 += selu_f(sc2 * bf2f((short)(wA[1] & 0xffff)) + sh2);
            a3 += selu_f(sc3 * bf2f((short)(wA[1] >> 16)) + sh3);
            a0 += selu_f(sc0 * bf2f((short)(wB[0] & 0xffff)) + sh0);
            a1 += selu_f(sc1 * bf2f((short)(wB[0] >> 16)) + sh1);
            a2 += selu_f(sc2 * bf2f((short)(wB[1] & 0xffff)) + sh2);
            a3 += selu_f(sc3 * bf2f((short)(wB[1] >> 16)) + sh3);
        }
        for (; j < cnt; j += 2) {
            if (j + h < cnt) {
                u32x2 w = ldnt_u2(base + (size_t)(j + h) * 128);
                a0 += selu_f(sc0 * bf2f((short)(w[0] & 0xffff)) + sh0);
                a1 += selu_f(sc1 * bf2f((short)(w[0] >> 16)) + sh1);
                a2 += selu_f(sc2 * bf2f((short)(w[1] & 0xffff)) + sh2);
                a3 += selu_f(sc3 * bf2f((short)(w[1] >> 16)) + sh3);
            }
        }
        a0 += __shfl_xor(a0, 32); a1 += __shfl_xor(a1, 32);
        a2 += __shfl_xor(a2, 32); a3 += __shfl_xor(a3, 32);
        if (h == 0) {
            const float inv = 1.0f / fmaxf((float)cnt, 1.0f);
            u32x2 o;
            o[0] = pack2(a0 * inv, a1 * inv);
            o[1] = pack2(a2 * inv, a3 * inv);
            *(u32x2*)(Aggm + (size_t)v * 128 + t * 4) = o;
        }
    }
}

// ---------------------------------------------------------------------------
// gemm3: T2p = packed([x, Aggm(packed), u[batch]] @ W2a' + (deg>0)*cb) ; fused stats
__global__ __launch_bounds__(256) void gemm3_node(
    const float* __restrict__ x, const short* __restrict__ Aggm,
    const float* __restrict__ u, const int* __restrict__ batch,
    const int* __restrict__ CNTi, const float* __restrict__ cb,
    const short* __restrict__ Wp, short* __restrict__ T2p,
    float* __restrict__ stats, int N)
{
    const int lane = threadIdx.x & 63, wave = threadIdx.x >> 6;
    const int m0 = blockIdx.x * 128 + wave * 32;
    const bool active = (m0 < N);   // N % 32 == 0
    const int lr = lane & 15, lg = lane >> 4;
    __shared__ float ls[256];
    ls[threadIdx.x] = 0.f;
    __syncthreads();

    if (active) {
        const int v0 = m0 + lr, v1 = m0 + 16 + lr;
        const float* u0 = u + (size_t)batch[v0] * 128;
        const float* u1 = u + (size_t)batch[v1] * 128;

        f32x4 acc[2][8];
#pragma unroll
        for (int t = 0; t < 2; ++t)
#pragma unroll
            for (int n = 0; n < 8; ++n) acc[t][n] = (f32x4){0.f, 0.f, 0.f, 0.f};

#pragma unroll
        for (int kb = 0; kb < 12; ++kb) {
            bfrag a0, a1;
            if (kb >= 4 && kb < 8) {
                a0 = *(const bfrag*)(Aggm + (size_t)v0 * 128 + (kb - 4) * 32 + lg * 8);
                a1 = *(const bfrag*)(Aggm + (size_t)v1 * 128 + (kb - 4) * 32 + lg * 8);
            } else {
                const float *p0, *p1;
                if (kb < 4) {
                    p0 = x + (size_t)v0 * 128 + kb * 32 + lg * 8;
                    p1 = x + (size_t)v1 * 128 + kb * 32 + lg * 8;
                } else {
                    p0 = u0 + (kb - 8) * 32 + lg * 8;
                    p1 = u1 + (kb - 8) * 32 + lg * 8;
                }
                a0 = load8f_bf(p0);
                a1 = load8f_bf(p1);
            }
            const short* wb = Wp + (size_t)kb * 4096;
#pragma unroll
            for (int n0 = 0; n0 < 8; ++n0) {
                bfrag b = *(const bfrag*)(wb + ((n0 * 16 + lr) * 4 + lg) * 8);
                acc[0][n0] = __builtin_amdgcn_mfma_f32_16x16x32_bf16(a0, b, acc[0][n0], 0, 0, 0);
                acc[1][n0] = __builtin_amdgcn_mfma_f32_16x16x32_bf16(a1, b, acc[1][n0], 0, 0, 0);
            }
        }
        // epilogue: + flag*cb, stats, packed store
        float cbl[8];
#pragma unroll
        for (int n0 = 0; n0 < 8; ++n0) cbl[n0] = cb[n0 * 16 + lr];
        float ps[8], qs[8];
#pragma unroll
        for (int n0 = 0; n0 < 8; ++n0) { ps[n0] = 0.f; qs[n0] = 0.f; }
#pragma unroll
        for (int t = 0; t < 2; ++t) {
            const int rbase = m0 + t * 16 + lg * 4;
            float fl[4];
#pragma unroll
            for (int r = 0; r < 4; ++r) fl[r] = (CNTi[rbase + r] > 0) ? 1.f : 0.f;
#pragma unroll
            for (int r = 0; r < 4; ++r) {
                bfrag o;
#pragma unroll
                for (int n0 = 0; n0 < 8; ++n0) {
                    float v = acc[t][n0][r] + fl[r] * cbl[n0];
                    ps[n0] += v; qs[n0] += v * v;
                    o[n0] = f2bf(v);
                }
                *(bfrag*)(T2p + (size_t)(rbase + r) * 128 + lr * 8) = o;
            }
        }
#pragma unroll
        for (int n0 = 0; n0 < 8; ++n0) {
            const int c = n0 * 16 + lr;
            float p = ps[n0], q = qs[n0];
            p += __shfl_xor(p, 16); p += __shfl_xor(p, 32);
            q += __shfl_xor(q, 16); q += __shfl_xor(q, 32);
            if (lg == 0) { atomicAdd(&ls[c], p); atomicAdd(&ls[128 + c], q); }
        }
    }
    __syncthreads();
    atomicAdd(&stats[threadIdx.x], ls[threadIdx.x]);
}

// Node GEMM2: out = selu(BN2(T2p)) @ W2b' + b2b   (f32 true-order output)
__global__ __launch_bounds__(256) void gemm4_node(
    const short* __restrict__ T2p, const float* __restrict__ stats,
    const float* __restrict__ g2, const float* __restrict__ be2,
    const short* __restrict__ Wp, const float* __restrict__ b2b,
    float* __restrict__ out, int N, float invR)
{
    __shared__ float ls_sc[128], ls_sh[128];
    if (threadIdx.x < 128) {
        int c = threadIdx.x;                     // true col
        float mean = stats[c] * invR;
        float var = stats[128 + c] * invR - mean * mean;
        float sc = g2[c] * rsqrtf(var + BN_EPS);
        ls_sc[c] = sc;
        ls_sh[c] = be2[c] - mean * sc;
    }
    __syncthreads();

    const int lane = threadIdx.x & 63, wave = threadIdx.x >> 6;
    const int m0 = blockIdx.x * 128 + wave * 32;
    if (m0 >= N) return;   // N % 32 == 0
    const int lr = lane & 15, lg = lane >> 4;
    const int e0 = m0 + lr, e1 = m0 + 16 + lr;

    f32x4 acc[2][8];
#pragma unroll
    for (int n0 = 0; n0 < 8; ++n0) {
        float bias = b2b[n0 * 16 + lr];
        acc[0][n0] = (f32x4){bias, bias, bias, bias};
        acc[1][n0] = (f32x4){bias, bias, bias, bias};
    }
#pragma unroll
    for (int kb = 0; kb < 4; ++kb) {
        // packed pos p = kb*32+lg*8+j  ->  true col j*16 + kb*4 + lg
        float scl[8], shf[8];
#pragma unroll
        for (int j = 0; j < 8; ++j) {
            int c = j * 16 + kb * 4 + lg;
            scl[j] = ls_sc[c];
            shf[j] = ls_sh[c];
        }
        bfrag r0 = *(const bfrag*)(T2p + (size_t)e0 * 128 + kb * 32 + lg * 8);
        bfrag r1 = *(const bfrag*)(T2p + (size_t)e1 * 128 + kb * 32 + lg * 8);
        bfrag a0, a1;
#pragma unroll
        for (int j = 0; j < 8; ++j) {
            a0[j] = f2bf(selu_f(bf2f(r0[j]) * scl[j] + shf[j]));
            a1[j] = f2bf(selu_f(bf2f(r1[j]) * scl[j] + shf[j]));
        }
        const short* wb = Wp + (size_t)kb * 4096;
#pragma unroll
        for (int n0 = 0; n0 < 8; ++n0) {
            bfrag b = *(const bfrag*)(wb + ((n0 * 16 + lr) * 4 + lg) * 8);
            acc[0][n0] = __builtin_amdgcn_mfma_f32_16x16x32_bf16(a0, b, acc[0][n0], 0, 0, 0);
            acc[1][n0] = __builtin_amdgcn_mfma_f32_16x16x32_bf16(a1, b, acc[1][n0], 0, 0, 0);
        }
    }
#pragma unroll
    for (int t = 0; t < 2; ++t) {
        const int rbase = m0 + t * 16 + lg * 4;
#pragma unroll
        for (int n0 = 0; n0 < 8; ++n0) {
            const int c = n0 * 16 + lr;
#pragma unroll
            for (int r = 0; r < 4; ++r)
                __builtin_nontemporal_store(acc[t][n0][r],
                    out + (size_t)(rbase + r) * 128 + c);
        }
    }
}

// ---------------------------------------------------------------------------
// Workspace layout (bytes):
//   0        Wp1x 32768  | 32768 Wp1e 16384 | 49152 Wp2a 98304 | 147456 Wp2b 32768
//   245760   cb 512
//   246272   stats1 1024 | 247296 stats2 1024
//   250368   CNTi 400000 | 650368 OFF 400000
//   1050368  BSUM 1024   | 1051392 BOFF 1024
//   1052416  SPOS 3200000
//   4252416  Aggm bf16 100000x128 (25600000)
//   29852416 Xap bf16 100000x128 (25600000)  [phase2: T2p overlays]
//   55452416 T1p bf16 800000x128 (204800000)  [CSR-sorted row order]
//   total: 260252416
// ---------------------------------------------------------------------------
extern "C" void kernel_launch(void* const* d_in, const int* in_sizes, int n_in,
                              void* d_out, int out_size, void* d_ws, size_t ws_size,
                              hipStream_t stream)
{
    const float* x   = (const float*)d_in[0];
    const float* ea  = (const float*)d_in[1];
    const float* u   = (const float*)d_in[2];
    const float* W1a = (const float*)d_in[3];
    // d_in[4] = b1a: cancels in BN1
    const float* g1  = (const float*)d_in[5];
    const float* be1 = (const float*)d_in[6];
    const float* W1b = (const float*)d_in[7];
    const float* b1b = (const float*)d_in[8];
    const float* W2a = (const float*)d_in[9];
    // d_in[10] = b2a: cancels in BN2
    const float* g2  = (const float*)d_in[11];
    const float* be2 = (const float*)d_in[12];
    const float* W2b = (const float*)d_in[13];
    const float* b2b = (const float*)d_in[14];
    const int* ei    = (const int*)d_in[15];
    const int* rowI  = ei;
    const int* colI  = ei + N_EDGES;
    const int* batch = (const int*)d_in[16];
    float* out = (float*)d_out;

    if (ws_size < 260252416ull) return;

    char* ws = (char*)d_ws;
    short* Wp1x   = (short*)(ws + 0);
    short* Wp1e   = (short*)(ws + 32768);
    short* Wp2a   = (short*)(ws + 49152);
    short* Wp2b   = (short*)(ws + 147456);
    float* cb     = (float*)(ws + 245760);
    float* stats1 = (float*)(ws + 246272);
    float* stats2 = (float*)(ws + 247296);
    int*   CNTi   = (int*)(ws + 250368);
    int*   OFF    = (int*)(ws + 650368);
    int*   BSUM   = (int*)(ws + 1050368);
    int*   BOFF   = (int*)(ws + 1051392);
    int*   SPOS   = (int*)(ws + 1052416);
    short* Aggm   = (short*)(ws + 4252416);
    short* Xap    = (short*)(ws + 29852416ull);
    short* T2p    = (short*)(ws + 29852416ull);   // overlays Xap (dead after gemm1n)
    short* T1p    = (short*)(ws + 55452416ull);

    hipMemsetAsync(stats1, 0, 2048, stream);      // stats1, stats2
    hipMemsetAsync(CNTi, 0, 400000, stream);

    // all weight prep + histogram: one kernel
    prep<<<353 + (N_EDGES + 255) / 256, 256, 0, stream>>>(
        W1a, W1b, b1b, W2a, W2b, Wp1x, Wp1e, Wp2a, Wp2b, cb, colI, CNTi, N_EDGES);

    // CSR scan + inverse-perm fill
    scan1<<<98, 1024, 0, stream>>>(CNTi, OFF, BSUM, N_NODES);
    scan2<<<1, 128, 0, stream>>>(BSUM, BOFF, 98);
    scan3<<<98, 1024, 0, stream>>>(OFF, BOFF, N_NODES);
    fill_k<<<(N_EDGES + 255) / 256, 256, 0, stream>>>(colI, OFF, SPOS, N_EDGES);

    // node-side half of edge layer 1
    gemmX<<<(N_NODES + 127) / 128, 256, 0, stream>>>(x, Wp1x, Xap, N_NODES);

    // edge layer 1 (natural read order, sorted write order) + stats
    gemm1n<<<2048, 256, 0, stream>>>(ea, rowI, SPOS, Wp1e, Xap, T1p, stats1, N_EDGES);

    // segmented selu-mean over bucket-contiguous T1p; BN1 inline
    segsel<<<2048, 256, 0, stream>>>(T1p, stats1, g1, be1, OFF, CNTi, Aggm,
                                     N_NODES, 1.0f / (float)N_EDGES);

    // node MLP
    gemm3_node<<<(N_NODES + 127) / 128, 256, 0, stream>>>(x, Aggm, u, batch, CNTi, cb,
                                                          Wp2a, T2p, stats2, N_NODES);
    gemm4_node<<<(N_NODES + 127) / 128, 256, 0, stream>>>(T2p, stats2, g2, be2, Wp2b, b2b,
                                                          out, N_NODES, 1.0f / (float)N_NODES);
}